// Round 4
// baseline (525.823 us; speedup 1.0000x reference)
//
#include <hip/hip_runtime.h>
#include <float.h>

// Shapes (fixed by the problem)
#define Bsz 2
#define Ssz 4096
#define Hsz 12
#define Gsz 64
#define Wsz 513
#define Csz (Gsz + Wsz)       // 577 channels
#define ROW (Hsz * Csz)       // 6924 floats per (b,s) row  (= 12*577, key identity)
#define HALF 256
#define RPB 8                 // rows per block
#define NSLOT (Gsz + RPB - 1 + Wsz)   // 64 global slots + 520 window slots = 584
#define NF4 (RPB * ROW / 4)   // 13848 float4 per block

// Workspace layout (floats)
#define PSUM_SZ ((size_t)Bsz * Ssz)   // 8192
#define GACC_SZ ((size_t)Bsz * Gsz)   // 128

// Bank swizzle: lanes hit slots spaced 4 apart (each lane owns 4 consecutive
// elements) -> stride-4 on 32 banks = 8-way conflict. (s&3)*146 + (s>>2) is a
// bijection on [0,584) that makes each ds_add instruction stride-1 across lanes.
__device__ __forceinline__ int SWZ(int s) { return ((s & 3) * 146) + (s >> 2); }

// K1: flat float4 streaming + unified LDS accumulator.
// Block = 256 threads, 8 consecutive rows (same b). Element at flat offset e
// (within the 8-row chunk) has channel c = e mod 577 (since ROW = 12*577) and
// row r = e / ROW. c<64 -> global-channel slot c; else window slot c+r, which
// equals output index i = s0 + slot - 320 by construction (collisions at row
// boundaries are *correct* merges). ds_add_f32 handles all cross-lane and
// cross-row aliasing -> only 2 barriers per block, no staging round-trip.
__global__ __launch_bounds__(256) void k1_fused(
    const float* __restrict__ probs, const float* __restrict__ mask,
    float* __restrict__ psum, float* __restrict__ gacc)
{
    __shared__ float U[NSLOT];        // 2,336 B
    __shared__ float scl[RPB + 1];
    const int t = threadIdx.x;
    const int row0 = blockIdx.x * RPB;
    const int b = row0 / Ssz;

    for (int u = t; u < NSLOT; u += 256) U[u] = 0.f;
    if (t < RPB) scl[t] = (mask[row0 + t] < 0.f) ? 0.f : 1.f;
    if (t == RPB) scl[RPB] = 0.f;     // guard for final r increment
    __syncthreads();

    const float4* __restrict__ src = (const float4*)(probs + (size_t)row0 * ROW);
    int c = 4 * t; if (c >= Csz) c -= Csz;   // c = (4*fi) mod 577
    int rowpos = 4 * t;                      // position within current row
    int r = 0;
    float sc = scl[0];

    for (int fi = t; fi < NF4; fi += 256) {
        float4 v = src[fi];
        float vv[4] = {v.x, v.y, v.z, v.w};
        #pragma unroll
        for (int j = 0; j < 4; ++j) {
            int cj = c + j; if (cj >= Csz) cj -= Csz;        // float4 may wrap c once
            int slot = (cj < Gsz) ? cj : cj + r;             // r uniform in a float4 (ROW%4==0)
            atomicAdd(&U[SWZ(slot)], vv[j] * sc);
        }
        c += 447; if (c >= Csz) c -= Csz;    // 1024 mod 577 = 447
        rowpos += 1024;
        if (rowpos >= ROW) { rowpos -= ROW; ++r; sc = scl[r]; }
    }
    __syncthreads();

    // flush: slot<64 -> gacc; else output i = s0 + slot - 320
    const int s0 = row0 - b * Ssz;
    for (int slot = t; slot < NSLOT; slot += 256) {
        float val = U[SWZ(slot)];
        if (slot < Gsz) {
            atomicAdd(&gacc[b * Gsz + slot], val);
        } else {
            int i = s0 + slot - (Gsz + HALF);
            if (i >= 0 && i < Ssz) atomicAdd(&psum[b * Ssz + i], val);
        }
    }
}

// K4: fused scatter (honors index arrays) + per-batch max + scores + mask.
// grid = B, block = 1024 (16 waves).
__global__ __launch_bounds__(1024) void k4_final(
    const float* __restrict__ psum, const float* __restrict__ gacc,
    const float* __restrict__ thr_p,
    const int* __restrict__ loc_b, const int* __restrict__ loc_i,
    const int* __restrict__ glob_b, const int* __restrict__ glob_i,
    int n_idx, float* __restrict__ out)
{
    __shared__ float p_lds[Ssz];   // 16 KiB
    __shared__ float red[16];
    const int b = blockIdx.x;
    const int t = threadIdx.x;
    const float* p = psum + (size_t)b * Ssz;

    for (int i = t; i < Ssz; i += 1024) p_lds[i] = p[i];
    __syncthreads();

    if (t < n_idx && loc_b[t] == b)
        atomicAdd(&p_lds[loc_i[t]], gacc[glob_b[t] * Gsz + glob_i[t]]);
    __syncthreads();

    float m = -FLT_MAX;
    for (int i = t; i < Ssz; i += 1024) m = fmaxf(m, p_lds[i]);
    #pragma unroll
    for (int off = 32; off >= 1; off >>= 1) m = fmaxf(m, __shfl_down(m, off, 64));

    const int wave = t >> 6, lane = t & 63;
    if (lane == 0) red[wave] = m;
    __syncthreads();
    if (t == 0) {
        float mm = red[0];
        #pragma unroll
        for (int w = 1; w < 16; ++w) mm = fmaxf(mm, red[w]);
        red[0] = mm;
    }
    __syncthreads();
    const float mx = red[0];
    const float thr = fmaxf(1e-5f, thr_p[0]);

    for (int i = t; i < Ssz; i += 1024) {
        float sc = p_lds[i] / mx;
        out[(size_t)Bsz * Ssz + (size_t)b * Ssz + i] = sc;        // scores (output 1)
        out[(size_t)b * Ssz + i] = (sc < thr) ? -10000.f : 0.f;   // mask (output 0)
    }
}

extern "C" void kernel_launch(void* const* d_in, const int* in_sizes, int n_in,
                              void* d_out, int out_size, void* d_ws, size_t ws_size,
                              hipStream_t stream)
{
    const float* mask  = (const float*)d_in[0];
    const float* probs = (const float*)d_in[1];
    const float* thr   = (const float*)d_in[2];
    // d_in[3] = max_num_global_attn_indices (hard-coded as Gsz)
    const int* loc_b  = (const int*)d_in[4];
    const int* loc_i  = (const int*)d_in[5];
    const int* glob_b = (const int*)d_in[6];
    const int* glob_i = (const int*)d_in[7];
    const int n_idx = in_sizes[4];

    float* psum = (float*)d_ws;
    float* gacc = psum + PSUM_SZ;
    float* out  = (float*)d_out;

    // zero psum + gacc (ws is poisoned 0xAA before every launch)
    hipMemsetAsync(psum, 0, (PSUM_SZ + GACC_SZ) * sizeof(float), stream);

    k1_fused<<<dim3(Bsz * Ssz / RPB), dim3(256), 0, stream>>>(probs, mask, psum, gacc);
    k4_final<<<dim3(Bsz), dim3(1024), 0, stream>>>(psum, gacc, thr,
                                                   loc_b, loc_i, glob_b, glob_i,
                                                   n_idx, out);
}

// Round 5
// 387.248 us; speedup vs baseline: 1.3578x; 1.3578x over previous
//
#include <hip/hip_runtime.h>
#include <float.h>

// Shapes (fixed by the problem)
#define Bsz 2
#define Ssz 4096
#define Hsz 12
#define Gsz 64
#define Wsz 513
#define Csz (Gsz + Wsz)       // 577 channels
#define ROW (Hsz * Csz)       // 6924 floats per (b,s) row
#define HALF 256
#define RPB 8                 // rows per block
#define NWIN (RPB - 1 + Wsz)  // 520 window slots
#define WPAD 528              // 4*132, swizzle domain

// Workspace layout (floats)
#define PSUM_SZ ((size_t)Bsz * Ssz)   // 8192
#define GACC_SZ ((size_t)Bsz * Gsz)   // 128

// ds_add lanes hit slots spaced 4 apart (thread owns 4 consecutive window
// cols) -> stride-4 = 8-way bank conflict. (s&3)*132 + (s>>2) is a bijection
// on [0,528) making each ds_add instruction stride-1 across lanes.
__device__ __forceinline__ int SWZ(int s) { return ((s & 3) * 132) + (s >> 2); }

// K1: direct-from-global, register h-sum, LDS-atomic diag window.
// Block = 192 threads (3 waves), 8 consecutive rows (same b).
// Thread g<16: global channels 4g..4g+3 (register acc across r,h).
// Thread 16<=g<144: window cols 4g-64..4g-61; per row: 12 independent
// coalesced float4 loads (one per h), register-sum, 4 ds_add_f32.
// Thread g==144: scalar channel 576. No barriers in the row loop.
__global__ __launch_bounds__(192) void k1_fused(
    const float* __restrict__ probs, const float* __restrict__ mask,
    float* __restrict__ psum, float* __restrict__ gacc)
{
    __shared__ float win[WPAD];    // 2,112 B
    const int t = threadIdx.x;
    const int row0 = blockIdx.x * RPB;
    const int b = row0 / Ssz;

    for (int u = t; u < WPAD; u += 192) win[u] = 0.f;
    __syncthreads();

    float scl[RPB];
    #pragma unroll
    for (int r = 0; r < RPB; ++r)
        scl[r] = (mask[row0 + r] < 0.f) ? 0.f : 1.f;

    const float* __restrict__ base = probs + (size_t)row0 * ROW;

    if (t < 16) {
        // global channels 4t..4t+3
        float ax = 0.f, ay = 0.f, az = 0.f, aw = 0.f;
        for (int r = 0; r < RPB; ++r) {
            float sx = 0.f, sy = 0.f, sz = 0.f, sw = 0.f;
            #pragma unroll
            for (int h = 0; h < Hsz; ++h) {
                float4 v = *(const float4*)(base + (size_t)r * ROW + h * Csz + 4 * t);
                sx += v.x; sy += v.y; sz += v.z; sw += v.w;
            }
            ax += sx * scl[r]; ay += sy * scl[r]; az += sz * scl[r]; aw += sw * scl[r];
        }
        atomicAdd(&gacc[b * Gsz + 4 * t + 0], ax);
        atomicAdd(&gacc[b * Gsz + 4 * t + 1], ay);
        atomicAdd(&gacc[b * Gsz + 4 * t + 2], az);
        atomicAdd(&gacc[b * Gsz + 4 * t + 3], aw);
    } else if (t < 144) {
        const int w0 = 4 * t - Gsz;      // window col base (multiple of 4)
        for (int r = 0; r < RPB; ++r) {
            float sx = 0.f, sy = 0.f, sz = 0.f, sw = 0.f;
            #pragma unroll
            for (int h = 0; h < Hsz; ++h) {
                float4 v = *(const float4*)(base + (size_t)r * ROW + h * Csz + 4 * t);
                sx += v.x; sy += v.y; sz += v.z; sw += v.w;
            }
            const float sc = scl[r];
            atomicAdd(&win[SWZ(w0 + r + 0)], sx * sc);
            atomicAdd(&win[SWZ(w0 + r + 1)], sy * sc);
            atomicAdd(&win[SWZ(w0 + r + 2)], sz * sc);
            atomicAdd(&win[SWZ(w0 + r + 3)], sw * sc);
        }
    } else if (t == 144) {
        // channel 576 -> window col 512
        for (int r = 0; r < RPB; ++r) {
            float s = 0.f;
            #pragma unroll
            for (int h = 0; h < Hsz; ++h)
                s += base[(size_t)r * ROW + h * Csz + 576];
            atomicAdd(&win[SWZ(512 + r)], s * scl[r]);
        }
    }
    __syncthreads();

    // flush: window slot w -> output i = s0 + w - 256
    const int s0 = row0 - b * Ssz;
    for (int w = t; w < NWIN; w += 192) {
        const int i = s0 + w - HALF;
        if (i >= 0 && i < Ssz) atomicAdd(&psum[b * Ssz + i], win[SWZ(w)]);
    }
}

// K4: fused scatter (honors index arrays) + per-batch max + scores + mask.
// grid = B, block = 1024 (16 waves).
__global__ __launch_bounds__(1024) void k4_final(
    const float* __restrict__ psum, const float* __restrict__ gacc,
    const float* __restrict__ thr_p,
    const int* __restrict__ loc_b, const int* __restrict__ loc_i,
    const int* __restrict__ glob_b, const int* __restrict__ glob_i,
    int n_idx, float* __restrict__ out)
{
    __shared__ float p_lds[Ssz];   // 16 KiB
    __shared__ float red[16];
    const int b = blockIdx.x;
    const int t = threadIdx.x;
    const float4* p4 = (const float4*)(psum + (size_t)b * Ssz);

    ((float4*)p_lds)[t] = p4[t];   // 1024 float4 = 4096 floats
    __syncthreads();

    if (t < n_idx && loc_b[t] == b)
        atomicAdd(&p_lds[loc_i[t]], gacc[glob_b[t] * Gsz + glob_i[t]]);
    __syncthreads();

    float m = -FLT_MAX;
    for (int i = t; i < Ssz; i += 1024) m = fmaxf(m, p_lds[i]);
    #pragma unroll
    for (int off = 32; off >= 1; off >>= 1) m = fmaxf(m, __shfl_down(m, off, 64));

    const int wave = t >> 6, lane = t & 63;
    if (lane == 0) red[wave] = m;
    __syncthreads();
    if (t == 0) {
        float mm = red[0];
        #pragma unroll
        for (int w = 1; w < 16; ++w) mm = fmaxf(mm, red[w]);
        red[0] = mm;
    }
    __syncthreads();
    const float mx = red[0];
    const float thr = fmaxf(1e-5f, thr_p[0]);

    for (int i = t; i < Ssz; i += 1024) {
        float sc = p_lds[i] / mx;
        out[(size_t)Bsz * Ssz + (size_t)b * Ssz + i] = sc;        // scores (output 1)
        out[(size_t)b * Ssz + i] = (sc < thr) ? -10000.f : 0.f;   // mask (output 0)
    }
}

extern "C" void kernel_launch(void* const* d_in, const int* in_sizes, int n_in,
                              void* d_out, int out_size, void* d_ws, size_t ws_size,
                              hipStream_t stream)
{
    const float* mask  = (const float*)d_in[0];
    const float* probs = (const float*)d_in[1];
    const float* thr   = (const float*)d_in[2];
    // d_in[3] = max_num_global_attn_indices (hard-coded as Gsz)
    const int* loc_b  = (const int*)d_in[4];
    const int* loc_i  = (const int*)d_in[5];
    const int* glob_b = (const int*)d_in[6];
    const int* glob_i = (const int*)d_in[7];
    const int n_idx = in_sizes[4];

    float* psum = (float*)d_ws;
    float* gacc = psum + PSUM_SZ;
    float* out  = (float*)d_out;

    // zero psum + gacc (ws is poisoned 0xAA before every launch)
    hipMemsetAsync(psum, 0, (PSUM_SZ + GACC_SZ) * sizeof(float), stream);

    k1_fused<<<dim3(Bsz * Ssz / RPB), dim3(192), 0, stream>>>(probs, mask, psum, gacc);
    k4_final<<<dim3(Bsz), dim3(1024), 0, stream>>>(psum, gacc, thr,
                                                   loc_b, loc_i, glob_b, glob_i,
                                                   n_idx, out);
}